// Round 9
// baseline (23.696 us; speedup 1.0000x reference)
//
#include <hip/hip_runtime.h>

#define NBINS 100
#define NATOM 1024
#define NBLK  256
#define NWAVE 16
#define HPAD  124            // 3 under + 100 bins + junk region: no bound checks
#define GSTR  136            // sub-hist stride (floats): 136%32=8 -> bank stagger
#define WIN   8              // ±4 sigma window; tail < 3.4e-4 rel
#define QCAP  320            // 256 max passing + 64 sentinel pads
#define PI_F 3.14159265358979323846f

// 256 blocks x 1024 threads; block handles rows i0..i0+3, thread owns column j.
// Phase A: dense PBC distances; passing dsq compacted into per-wave LDS queue.
// Phase B (transposed drain): 8 pairs per wave-issue, 8 lanes per pair
//   (lane>>3 = pair slot g, lane&7 = bin offset k). Each slot g writes its OWN
//   sub-hist shw[wave][g][*] -> zero same-address LDS-atomic collisions
//   (the R4/R6/R8 evidence says same-address RMW serialization was the cost).
//   One exp + one ds_add per lane per issue; <=2-way bank conflicts (free).
// Queue sentinel dsq=31 -> d=5.568 -> bins 110..117: junk region, never read.
// 2-node pipeline: grid-wide sync costs 60-100us on this chip (R3/R7) - avoid.
__global__ __launch_bounds__(1024) void rdf_hist(const float* __restrict__ xyz,
                                                 const float* __restrict__ cell,
                                                 float* __restrict__ ws) {
    const float cx = cell[0], cy = cell[1], cz = cell[2];
    const float hx = 0.5f * cx, hy = 0.5f * cy, hz = 0.5f * cz;
    const float coeff  = -0.5f * (99.0f * 99.0f) / (5.0f * 5.0f);  // -196.02
    const float cutsq  = 5.5f * 5.5f;
    const float DB     = 5.0f / 99.0f;
    const float INV_DB = 99.0f / 5.0f;

    __shared__ float shw[NWAVE][8][GSTR];     // 69632 B
    __shared__ float qd[NWAVE][QCAP];         // 20480 B
    for (int k = threadIdx.x; k < NWAVE * 8 * GSTR; k += 1024)
        (&shw[0][0][0])[k] = 0.0f;
    __syncthreads();

    const int wave = threadIdx.x >> 6;
    const int lane = threadIdx.x & 63;
    const unsigned long long ltmask = (1ULL << lane) - 1ULL;

    // thread owns atom j (coalesced load)
    const int j = threadIdx.x;
    const float xj = xyz[3 * j + 0];
    const float yj = xyz[3 * j + 1];
    const float zj = xyz[3 * j + 2];

    // ---- phase A: compact passing pairs into the per-wave queue ----
    int qcount = 0;                           // wave-uniform (ballot-derived)
    const int i0 = blockIdx.x * (NATOM / NBLK);
#pragma unroll
    for (int r = 0; r < NATOM / NBLK; ++r) {
        const int i = i0 + r;                 // block-uniform -> scalar loads
        const float xi = xyz[3 * i + 0];
        const float yi = xyz[3 * i + 1];
        const float zi = xyz[3 * i + 2];
        float dx = xj - xi;                   // dvec = xyz[j] - xyz[i]
        float dy = yj - yi;
        float dz = zj - zi;
        // minimum-image PBC, exact replication of reference shift rule
        dx += (dx < -hx ? cx : 0.0f) - (dx >= hx ? cx : 0.0f);
        dy += (dy < -hy ? cy : 0.0f) - (dy >= hy ? cy : 0.0f);
        dz += (dz < -hz ? cz : 0.0f) - (dz >= hz ? cz : 0.0f);
        const float dsq = dx * dx + dy * dy + dz * dz;
        const bool pass = (dsq != 0.0f) && (dsq < cutsq);
        const unsigned long long b = __ballot(pass);
        if (pass) qd[wave][qcount + __popcll(b & ltmask)] = dsq;
        qcount += __popcll(b);
    }
    // sentinel pad: d=sqrt(31)=5.568 -> base+3 = 110, writes bins 110..117 (junk)
    qd[wave][qcount + lane] = 31.0f;

    // ---- phase B: transposed drain, 8 pairs x 8 bin-lanes per issue ----
    const int g = lane >> 3;                  // pair slot -> own sub-hist
    const int k = lane & 7;                   // bin offset within window
    const int iters = (qcount + 7) >> 3;      // wave-uniform trip count
    for (int it = 0; it < iters; ++it) {
        const float dsq = qd[wave][it * 8 + g];   // 8-lane broadcast read
        const float d    = sqrtf(dsq);
        const int   base = (int)(d * INV_DB) - 3; // window [base, base+7]
        const float t    = d - (float)(base + k) * DB;
        atomicAdd(&shw[wave][g][base + 3 + k], __expf(coeff * t * t));
    }

    __syncthreads();
    if (threadIdx.x < NBINS) {
        float s = 0.0f;
#pragma unroll
        for (int w = 0; w < NWAVE; ++w)
#pragma unroll
            for (int g2 = 0; g2 < 8; ++g2) s += shw[w][g2][threadIdx.x + 3];
        // bin-major partial store: finalize's loads over blocks are coalesced
        ws[threadIdx.x * NBLK + blockIdx.x] = s;
    }
}

// single block, 1024 threads: reduce 256 partials/bin, normalize, emit outputs
__global__ __launch_bounds__(1024) void rdf_finalize(const float* __restrict__ ws,
                                                     float* __restrict__ out) {
    __shared__ float tot[NBINS];
    __shared__ float wsum[2];

    const int t = threadIdx.x;
    if (t < 8 * NBINS) {             // 8 threads per bin
        const int b = t >> 3, sub = t & 7;
        const float4* p = (const float4*)&ws[b * NBLK + sub * 32];
        float4 a0 = p[0], a1 = p[1], a2 = p[2], a3 = p[3];
        float4 a4 = p[4], a5 = p[5], a6 = p[6], a7 = p[7];
        float s = ((a0.x + a0.y + a0.z + a0.w) + (a1.x + a1.y + a1.z + a1.w))
                + ((a2.x + a2.y + a2.z + a2.w) + (a3.x + a3.y + a3.z + a3.w))
                + ((a4.x + a4.y + a4.z + a4.w) + (a5.x + a5.y + a5.z + a5.w))
                + ((a6.x + a6.y + a6.z + a6.w) + (a7.x + a7.y + a7.z + a7.w));
        s += __shfl_xor(s, 1, 64);   // butterfly within the 8-lane group
        s += __shfl_xor(s, 2, 64);
        s += __shfl_xor(s, 4, 64);
        if (sub == 0) tot[b] = s;
    }
    __syncthreads();

    const float v = (t < NBINS) ? tot[t] : 0.0f;
    if (t < 128) {
        float s = v;
        s += __shfl_xor(s, 1, 64);
        s += __shfl_xor(s, 2, 64);
        s += __shfl_xor(s, 4, 64);
        s += __shfl_xor(s, 8, 64);
        s += __shfl_xor(s, 16, 64);
        s += __shfl_xor(s, 32, 64);
        if ((t & 63) == 0) wsum[t >> 6] = s;
    }
    __syncthreads();
    const float total = wsum[0] + wsum[1];

    if (t < NBINS) {
        const float count = v / total;
        out[t] = count;                                   // output 0: count[100]
        const float b0 = 0.05f * (float)t;
        const float b1 = 0.05f * (float)(t + 1);
        const float vol = (4.0f * PI_F / 3.0f) * (b1 * b1 * b1 - b0 * b0 * b0);
        const float V = (4.0f / 3.0f) * PI_F * 125.0f;    // end^3 = 5^3
        out[2 * NBINS + 1 + t] = count * V / vol;         // output 2: rdf[100]
    }
    if (t < NBINS + 1) {
        out[NBINS + t] = 0.05f * (float)t;                // output 1: bins[101]
    }
}

extern "C" void kernel_launch(void* const* d_in, const int* in_sizes, int n_in,
                              void* d_out, int out_size, void* d_ws, size_t ws_size,
                              hipStream_t stream) {
    const float* xyz  = (const float*)d_in[0];
    const float* cell = (const float*)d_in[1];
    float* out = (float*)d_out;
    float* ws  = (float*)d_ws;

    rdf_hist<<<NBLK, 1024, 0, stream>>>(xyz, cell, ws);
    rdf_finalize<<<1, 1024, 0, stream>>>(ws, out);
}

// Round 10
// 16.864 us; speedup vs baseline: 1.4051x; 1.4051x over previous
//
#include <hip/hip_runtime.h>

#define NBINS 100
#define NATOM 1024
#define NBLK  256
#define NWAVE 16
#define HPAD  124            // 3 under + 100 bins + junk over-region: no bound checks
#define WIN   8              // ±4 sigma window (sigma == bin spacing); tail < 3.4e-4 rel
#define PI_F 3.14159265358979323846f

// Triangle-symmetric RDF: dsq(i,j)==dsq(j,i) BITWISE (negation is exact through
// the min-image shift rule, incl. dx==+-hx edges), and count is self-normalized
// (count/count.sum()), so histogramming only j>i pairs yields IDENTICAL output.
// 256 blocks x 1024 threads; block b owns rows {2b, 2b+1, 1022-2b, 1023-2b}
// -> exactly 2046 j>i pairs per block (perfect balance). Wave-uniform row skip
// when the wave's whole j-range is <= i. Windowed smear (8 bins) into per-wave
// padded LDS hists; block partials -> ws[bin*NBLK+blk]; no global atomics.
// 2-node pipeline: grid-wide handoff costs 85-100us on this chip (R3/R7).
__global__ __launch_bounds__(1024) void rdf_hist(const float* __restrict__ xyz,
                                                 const float* __restrict__ cell,
                                                 float* __restrict__ ws) {
    const float cx = cell[0], cy = cell[1], cz = cell[2];
    const float hx = 0.5f * cx, hy = 0.5f * cy, hz = 0.5f * cz;
    const float coeff  = -0.5f * (99.0f * 99.0f) / (5.0f * 5.0f);  // -196.02
    const float cutsq  = 5.5f * 5.5f;
    const float DB     = 5.0f / 99.0f;
    const float INV_DB = 99.0f / 5.0f;

    __shared__ float shw[NWAVE][HPAD];
    for (int k = threadIdx.x; k < NWAVE * HPAD; k += 1024)
        (&shw[0][0])[k] = 0.0f;
    __syncthreads();

    const int wave  = threadIdx.x >> 6;
    const int jmax  = (wave << 6) + 63;       // wave's largest j

    // thread owns atom j (coalesced load)
    const int j = threadIdx.x;
    const float xj = xyz[3 * j + 0];
    const float yj = xyz[3 * j + 1];
    const float zj = xyz[3 * j + 2];

    const int b2 = blockIdx.x * 2;
    const int rows[4] = { b2, b2 + 1, 1022 - b2, 1023 - b2 };

#pragma unroll
    for (int r = 0; r < 4; ++r) {
        const int i = rows[r];                // block-uniform -> scalar loads
        if (jmax <= i) continue;              // wave-uniform: no j>i in this wave
        const float xi = xyz[3 * i + 0];
        const float yi = xyz[3 * i + 1];
        const float zi = xyz[3 * i + 2];
        float dx = xj - xi;                   // dvec = xyz[j] - xyz[i]
        float dy = yj - yi;
        float dz = zj - zi;
        // minimum-image PBC, exact replication of reference shift rule
        dx += (dx < -hx ? cx : 0.0f) - (dx >= hx ? cx : 0.0f);
        dy += (dy < -hy ? cy : 0.0f) - (dy >= hy ? cy : 0.0f);
        dz += (dz < -hz ? cz : 0.0f) - (dz >= hz ? cz : 0.0f);
        const float dsq = dx * dx + dy * dy + dz * dz;
        if (j > i && dsq != 0.0f && dsq < cutsq) {
            const float d    = sqrtf(dsq);
            const int   base = (int)(d * INV_DB) - 3;   // window [base, base+7]
            const float t0   = d - (float)base * DB;
            float* h = &shw[wave][base + 3];            // base+3 in [0, 108]
#pragma unroll
            for (int k = 0; k < WIN; ++k) {
                const float t = t0 - (float)k * DB;     // k*DB folds to a constant
                atomicAdd(&h[k], __expf(coeff * t * t));
            }
        }
    }

    __syncthreads();
    if (threadIdx.x < NBINS) {
        float s = 0.0f;
#pragma unroll
        for (int w = 0; w < NWAVE; ++w) s += shw[w][threadIdx.x + 3];
        // bin-major partial store: finalize's loads over blocks are coalesced
        ws[threadIdx.x * NBLK + blockIdx.x] = s;
    }
}

// single block, 1024 threads: reduce 256 partials/bin, normalize, emit outputs
__global__ __launch_bounds__(1024) void rdf_finalize(const float* __restrict__ ws,
                                                     float* __restrict__ out) {
    __shared__ float tot[NBINS];
    __shared__ float wsum[2];

    const int t = threadIdx.x;
    if (t < 8 * NBINS) {             // 8 threads per bin
        const int b = t >> 3, sub = t & 7;
        const float4* p = (const float4*)&ws[b * NBLK + sub * 32];
        float4 a0 = p[0], a1 = p[1], a2 = p[2], a3 = p[3];
        float4 a4 = p[4], a5 = p[5], a6 = p[6], a7 = p[7];
        float s = ((a0.x + a0.y + a0.z + a0.w) + (a1.x + a1.y + a1.z + a1.w))
                + ((a2.x + a2.y + a2.z + a2.w) + (a3.x + a3.y + a3.z + a3.w))
                + ((a4.x + a4.y + a4.z + a4.w) + (a5.x + a5.y + a5.z + a5.w))
                + ((a6.x + a6.y + a6.z + a6.w) + (a7.x + a7.y + a7.z + a7.w));
        s += __shfl_xor(s, 1, 64);   // butterfly within the 8-lane group
        s += __shfl_xor(s, 2, 64);
        s += __shfl_xor(s, 4, 64);
        if (sub == 0) tot[b] = s;
    }
    __syncthreads();

    const float v = (t < NBINS) ? tot[t] : 0.0f;
    if (t < 128) {
        float s = v;
        s += __shfl_xor(s, 1, 64);
        s += __shfl_xor(s, 2, 64);
        s += __shfl_xor(s, 4, 64);
        s += __shfl_xor(s, 8, 64);
        s += __shfl_xor(s, 16, 64);
        s += __shfl_xor(s, 32, 64);
        if ((t & 63) == 0) wsum[t >> 6] = s;
    }
    __syncthreads();
    const float total = wsum[0] + wsum[1];

    if (t < NBINS) {
        const float count = v / total;
        out[t] = count;                                   // output 0: count[100]
        const float b0 = 0.05f * (float)t;
        const float b1 = 0.05f * (float)(t + 1);
        const float vol = (4.0f * PI_F / 3.0f) * (b1 * b1 * b1 - b0 * b0 * b0);
        const float V = (4.0f / 3.0f) * PI_F * 125.0f;    // end^3 = 5^3
        out[2 * NBINS + 1 + t] = count * V / vol;         // output 2: rdf[100]
    }
    if (t < NBINS + 1) {
        out[NBINS + t] = 0.05f * (float)t;                // output 1: bins[101]
    }
}

extern "C" void kernel_launch(void* const* d_in, const int* in_sizes, int n_in,
                              void* d_out, int out_size, void* d_ws, size_t ws_size,
                              hipStream_t stream) {
    const float* xyz  = (const float*)d_in[0];
    const float* cell = (const float*)d_in[1];
    float* out = (float*)d_out;
    float* ws  = (float*)d_ws;

    rdf_hist<<<NBLK, 1024, 0, stream>>>(xyz, cell, ws);
    rdf_finalize<<<1, 1024, 0, stream>>>(ws, out);
}

// Round 11
// 15.454 us; speedup vs baseline: 1.5333x; 1.0913x over previous
//
#include <hip/hip_runtime.h>

#define NBINS 100
#define NATOM 1024
#define NBLK  256
#define NWAVE 16
#define HPAD  120            // 2 under + 100 bins + junk over-region: no bound checks
#define WIN   6              // covers -2..+3.x sigma; omitted tail <= e^-4.5 per side
#define PI_F 3.14159265358979323846f

// Triangle-symmetric RDF: dsq(i,j)==dsq(j,i) BITWISE (negation is exact through
// the min-image shift rule), count is self-normalized -> j>i pairs only gives
// IDENTICAL output. Block b owns rows {2b, 2b+1, 1022-2b, 1023-2b} = 2046 pairs
// per block (perfect balance); wave-uniform row skip when jmax <= i.
// WIN=6 window (-2..+3 sigma) into per-wave padded LDS hists via exp2f
// (v_exp_f32 computes 2^x natively; log2e folded into coeff2).
// Block partials -> ws[bin*NBLK+blk]; 2-node pipeline (grid sync = 85-100us, dead).
__global__ __launch_bounds__(1024) void rdf_hist(const float* __restrict__ xyz,
                                                 const float* __restrict__ cell,
                                                 float* __restrict__ ws,
                                                 float* __restrict__ out) {
    const float cx = cell[0], cy = cell[1], cz = cell[2];
    const float hx = 0.5f * cx, hy = 0.5f * cy, hz = 0.5f * cz;
    // coeff2 = -0.5/width^2 * log2(e) = -196.02 * 1.4426950409
    const float coeff2 = -0.5f * (99.0f * 99.0f) / (5.0f * 5.0f) * 1.4426950409f;
    const float cutsq  = 5.5f * 5.5f;
    const float DB     = 5.0f / 99.0f;
    const float INV_DB = 99.0f / 5.0f;

    __shared__ float shw[NWAVE][HPAD];
    for (int k = threadIdx.x; k < NWAVE * HPAD; k += 1024)
        (&shw[0][0])[k] = 0.0f;
    __syncthreads();

    const int wave = threadIdx.x >> 6;
    const int jmax = (wave << 6) + 63;        // wave's largest j

    // thread owns atom j (coalesced load)
    const int j = threadIdx.x;
    const float xj = xyz[3 * j + 0];
    const float yj = xyz[3 * j + 1];
    const float zj = xyz[3 * j + 2];

    const int b2 = blockIdx.x * 2;
    const int rows[4] = { b2, b2 + 1, 1022 - b2, 1023 - b2 };

#pragma unroll
    for (int r = 0; r < 4; ++r) {
        const int i = rows[r];                // block-uniform -> scalar loads
        if (jmax <= i) continue;              // wave-uniform: no j>i in this wave
        const float xi = xyz[3 * i + 0];
        const float yi = xyz[3 * i + 1];
        const float zi = xyz[3 * i + 2];
        float dx = xj - xi;                   // dvec = xyz[j] - xyz[i]
        float dy = yj - yi;
        float dz = zj - zi;
        // minimum-image PBC, exact replication of reference shift rule
        dx += (dx < -hx ? cx : 0.0f) - (dx >= hx ? cx : 0.0f);
        dy += (dy < -hy ? cy : 0.0f) - (dy >= hy ? cy : 0.0f);
        dz += (dz < -hz ? cz : 0.0f) - (dz >= hz ? cz : 0.0f);
        const float dsq = dx * dx + dy * dy + dz * dz;
        if (j > i && dsq != 0.0f && dsq < cutsq) {
            const float d    = sqrtf(dsq);
            const int   base = (int)(d * INV_DB) - 2;   // window [base, base+5]
            const float t0   = d - (float)base * DB;
            float* h = &shw[wave][base + 2];            // base+2 in [0, 108]
#pragma unroll
            for (int k = 0; k < WIN; ++k) {
                const float t = t0 - (float)k * DB;     // k*DB folds to a constant
                atomicAdd(&h[k], exp2f(coeff2 * t * t));
            }
        }
    }

    __syncthreads();
    if (threadIdx.x < NBINS) {
        float s = 0.0f;
#pragma unroll
        for (int w = 0; w < NWAVE; ++w) s += shw[w][threadIdx.x + 2];
        // bin-major partial store: finalize's loads over blocks are coalesced
        ws[threadIdx.x * NBLK + blockIdx.x] = s;
    }
    // static output 1 (bins[101]): written here by block 0's idle threads,
    // no dependency on the reduction
    if (blockIdx.x == 0 && threadIdx.x >= 128 && threadIdx.x < 128 + NBINS + 1) {
        const int t = threadIdx.x - 128;
        out[NBINS + t] = 0.05f * (float)t;
    }
}

// single block, 1024 threads: reduce 256 partials/bin, normalize, emit count+rdf
__global__ __launch_bounds__(1024) void rdf_finalize(const float* __restrict__ ws,
                                                     float* __restrict__ out) {
    __shared__ float tot[NBINS];
    __shared__ float wsum[2];

    const int t = threadIdx.x;
    if (t < 8 * NBINS) {             // 8 threads per bin
        const int b = t >> 3, sub = t & 7;
        const float4* p = (const float4*)&ws[b * NBLK + sub * 32];
        float4 a0 = p[0], a1 = p[1], a2 = p[2], a3 = p[3];
        float4 a4 = p[4], a5 = p[5], a6 = p[6], a7 = p[7];
        float s = ((a0.x + a0.y + a0.z + a0.w) + (a1.x + a1.y + a1.z + a1.w))
                + ((a2.x + a2.y + a2.z + a2.w) + (a3.x + a3.y + a3.z + a3.w))
                + ((a4.x + a4.y + a4.z + a4.w) + (a5.x + a5.y + a5.z + a5.w))
                + ((a6.x + a6.y + a6.z + a6.w) + (a7.x + a7.y + a7.z + a7.w));
        s += __shfl_xor(s, 1, 64);   // butterfly within the 8-lane group
        s += __shfl_xor(s, 2, 64);
        s += __shfl_xor(s, 4, 64);
        if (sub == 0) tot[b] = s;
    }
    __syncthreads();

    const float v = (t < NBINS) ? tot[t] : 0.0f;
    if (t < 128) {
        float s = v;
        s += __shfl_xor(s, 1, 64);
        s += __shfl_xor(s, 2, 64);
        s += __shfl_xor(s, 4, 64);
        s += __shfl_xor(s, 8, 64);
        s += __shfl_xor(s, 16, 64);
        s += __shfl_xor(s, 32, 64);
        if ((t & 63) == 0) wsum[t >> 6] = s;
    }
    __syncthreads();
    const float total = wsum[0] + wsum[1];

    if (t < NBINS) {
        const float count = v / total;
        out[t] = count;                                   // output 0: count[100]
        const float b0 = 0.05f * (float)t;
        const float b1 = 0.05f * (float)(t + 1);
        const float vol = (4.0f * PI_F / 3.0f) * (b1 * b1 * b1 - b0 * b0 * b0);
        const float V = (4.0f / 3.0f) * PI_F * 125.0f;    // end^3 = 5^3
        out[2 * NBINS + 1 + t] = count * V / vol;         // output 2: rdf[100]
    }
}

extern "C" void kernel_launch(void* const* d_in, const int* in_sizes, int n_in,
                              void* d_out, int out_size, void* d_ws, size_t ws_size,
                              hipStream_t stream) {
    const float* xyz  = (const float*)d_in[0];
    const float* cell = (const float*)d_in[1];
    float* out = (float*)d_out;
    float* ws  = (float*)d_ws;

    rdf_hist<<<NBLK, 1024, 0, stream>>>(xyz, cell, ws, out);
    rdf_finalize<<<1, 1024, 0, stream>>>(ws, out);
}